// Round 14
// baseline (248.151 us; speedup 1.0000x reference)
//
#include <hip/hip_runtime.h>

#define HH 256
#define KK 8

typedef __attribute__((ext_vector_type(8))) short s16x8;
typedef __attribute__((ext_vector_type(4))) float f32x4;

__device__ __forceinline__ float bf2f(unsigned short u){ unsigned x=((unsigned)u)<<16; return __builtin_bit_cast(float,x); }
__device__ __forceinline__ unsigned f2bf(float f){ unsigned x=__builtin_bit_cast(unsigned,f); return (x+0x7fffu+((x>>16)&1u))>>16; }
__device__ __forceinline__ float sigmoidf(float x){ return __builtin_amdgcn_rcpf(1.0f + __expf(-x)); }

// ---- K1: all 4 weights f32 -> bf16.  grid (32,4) x 256thr ----
__global__ void cvt_w(const float* __restrict__ wa, const float* __restrict__ wu,
                      const float* __restrict__ wv, const float* __restrict__ wbm,
                      unsigned short* __restrict__ dst){
  const int w = blockIdx.y;
  const float* src = (w==0)? wa : (w==1)? wu : (w==2)? wv : wbm;
  const int i = blockIdx.x*256 + threadIdx.x;
  const float4* s = reinterpret_cast<const float4*>(src);
  float4 a = s[i*2], b = s[i*2+1];
  uint4 o;
  o.x = f2bf(a.x) | (f2bf(a.y)<<16);
  o.y = f2bf(a.z) | (f2bf(a.w)<<16);
  o.z = f2bf(b.x) | (f2bf(b.y)<<16);
  o.w = f2bf(b.z) | (f2bf(b.w)<<16);
  reinterpret_cast<uint4*>(dst + (size_t)w*65536)[i] = o;
}

// ---- K2: px[m][1024] = prev[m,:] @ [W_A|W_U|W_V|W_B]^T ----
// 512 thr / 8 waves (2 row-groups x 4 col-groups); wave tile 64x64
// (acc[4][4] -> AGPR-safe). As 64KB + B dbuf 2x32KB (256 cols x 64 k).
// 16 steps, ONE __syncthreads per step, reg-prefetch of next panel.
__global__ __launch_bounds__(512, 2)
void gemm_all(const float* __restrict__ prev,
              const unsigned short* __restrict__ wb,   // [1024][256] bf16 rows = out-cols
              unsigned short* __restrict__ px,         // [N][1024] bf16
              int n)
{
  __shared__ char smem[131072];        // As [0,64K) + Bs dbuf [64K,128K)
  char* const bsb = smem + 65536;
  const int tid = threadIdx.x;
  const int m0  = blockIdx.x * 128;
  const int lane = tid & 63, wid = tid >> 6;
  const int wr = wid >> 2, wc = wid & 3;   // 2 row-groups(64) x 4 col-groups(64)
  const int lm = lane & 15, kc = lane >> 4;

  // B staging coords: thread t covers panel-col t>>1, bytes (t&1)*64..+63
  const int colL = tid >> 1;
  const int ch0  = (tid & 1) * 64;
  const int cswz = (colL & 7) << 4;
  const char* wbc = reinterpret_cast<const char*>(wb);

  // ---- prefetch panel 0 (cols 0..255, k 0..63) into regs ----
  uint4 pre0, pre1, pre2, pre3;
  {
    const char* g = wbc + (size_t)colL*512 + ch0;
    pre0 = *reinterpret_cast<const uint4*>(g);
    pre1 = *reinterpret_cast<const uint4*>(g + 16);
    pre2 = *reinterpret_cast<const uint4*>(g + 32);
    pre3 = *reinterpret_cast<const uint4*>(g + 48);
  }

  // ---- stage A-tile: 128 rows x 256k, f32->bf16, swizzled ----
  #pragma unroll
  for (int it=0; it<8; ++it){
    const int c = it*512 + tid;
    const int row = c>>5, kch = c&31;
    const int gm = m0 + row;
    uint4 o = {0u,0u,0u,0u};
    if (gm < n){
      const float4* sp = reinterpret_cast<const float4*>(prev + (size_t)gm*HH + kch*8);
      float4 f0 = sp[0], f1 = sp[1];
      o.x=f2bf(f0.x)|(f2bf(f0.y)<<16);
      o.y=f2bf(f0.z)|(f2bf(f0.w)<<16);
      o.z=f2bf(f1.x)|(f2bf(f1.y)<<16);
      o.w=f2bf(f1.z)|(f2bf(f1.w)<<16);
    }
    *reinterpret_cast<uint4*>(smem + row*512 + ((kch*16) ^ ((row&7)<<4))) = o;
  }

  f32x4 acc[4][4];

  for (int q=0; q<16; ++q){
    const int cg = q>>2, ks = q&3;
    // write prefetched panel q into buf[q&1] (other buffer still being read)
    {
      char* bb = bsb + (q&1)*32768;
      *reinterpret_cast<uint4*>(bb + colL*128 + ((ch0      ) ^ cswz)) = pre0;
      *reinterpret_cast<uint4*>(bb + colL*128 + ((ch0 + 16 ) ^ cswz)) = pre1;
      *reinterpret_cast<uint4*>(bb + colL*128 + ((ch0 + 32 ) ^ cswz)) = pre2;
      *reinterpret_cast<uint4*>(bb + colL*128 + ((ch0 + 48 ) ^ cswz)) = pre3;
    }
    __syncthreads();               // panel q visible; readers of buf[q&1] (step q-2) done
    if (q < 15){                   // prefetch panel q+1 during compute
      const int p1 = q+1;
      const char* g = wbc + (size_t)(((p1>>2)*256) + colL)*512 + (p1&3)*128 + ch0;
      pre0 = *reinterpret_cast<const uint4*>(g);
      pre1 = *reinterpret_cast<const uint4*>(g + 16);
      pre2 = *reinterpret_cast<const uint4*>(g + 32);
      pre3 = *reinterpret_cast<const uint4*>(g + 48);
    }
    if (ks == 0){
      #pragma unroll
      for (int i=0;i<4;++i)
        #pragma unroll
        for (int j=0;j<4;++j) acc[i][j]=(f32x4){0.f,0.f,0.f,0.f};
    }
    const char* rb = bsb + (q&1)*32768;
    #pragma unroll
    for (int kk=0; kk<2; ++kk){
      s16x8 a[4];
      #pragma unroll
      for (int i=0;i<4;++i){
        const int row = wr*64 + i*16 + lm;
        a[i] = *reinterpret_cast<const s16x8*>(smem + row*512
                 + ((ks*128 + kk*64 + kc*16) ^ ((row&7)<<4)));
      }
      #pragma unroll
      for (int j=0;j<4;++j){
        const int brow = wc*64 + j*16 + lm;
        s16x8 b = *reinterpret_cast<const s16x8*>(rb + brow*128
                 + ((kk*64 + kc*16) ^ ((brow&7)<<4)));
        #pragma unroll
        for (int i=0;i<4;++i)
          acc[i][j] = __builtin_amdgcn_mfma_f32_16x16x32_bf16(a[i], b, acc[i][j], 0, 0, 0);
      }
    }
    if (ks == 3){                  // flush this 256-col group
      #pragma unroll
      for (int i=0;i<4;++i){
        #pragma unroll
        for (int r=0;r<4;++r){
          const int gm = m0 + wr*64 + i*16 + kc*4 + r;   // D: row=(lane>>4)*4+reg
          if (gm < n){
            unsigned short* dp = px + (size_t)gm*1024 + cg*256 + wc*64 + lm;
            #pragma unroll
            for (int j=0;j<4;++j) dp[j*16] = (unsigned short)f2bf(acc[i][j][r]);
          }
        }
      }
    }
  }
}

// ---- K3: gather epilogue. 64 lanes per node, 4 cols/lane; fat loads/stores. ----
__global__ __launch_bounds__(256)
void epilogue(const unsigned short* __restrict__ px,   // [N][4][256]: A,U,V,B
              const int* __restrict__ parent,
              const int* __restrict__ child,
              const int* __restrict__ mask,
              float* __restrict__ out,
              int n)
{
  const int e = blockIdx.x*4 + (threadIdx.x>>6);   // wave-uniform node
  if (e >= n) return;
  const int c4 = (threadIdx.x & 63) * 4;
  const int p  = parent[e];

  const unsigned short* rp = px + (size_t)p*1024 + c4;
  uint2 av = *reinterpret_cast<const uint2*>(rp);         // PA (4 bf16)
  uint2 uv = *reinterpret_cast<const uint2*>(rp + 256);   // PU
  const unsigned short* ap = reinterpret_cast<const unsigned short*>(&av);
  const unsigned short* up = reinterpret_cast<const unsigned short*>(&uv);

  float A[4], o[4], eta[4];
  #pragma unroll
  for (int j=0;j<4;++j){ A[j]=bf2f(ap[j]); o[j]=bf2f(up[j]); eta[j]=0.f; }

  int nm = 0;
  #pragma unroll
  for (int k=0;k<KK;++k){
    if (mask[(size_t)e*KK + k]){
      const unsigned short* rc = px + (size_t)child[(size_t)e*KK + k]*1024 + c4;
      uint2 pv = *reinterpret_cast<const uint2*>(rc + 512);   // PV
      uint2 pb = *reinterpret_cast<const uint2*>(rc + 768);   // PB
      const unsigned short* vp = reinterpret_cast<const unsigned short*>(&pv);
      const unsigned short* bp = reinterpret_cast<const unsigned short*>(&pb);
      #pragma unroll
      for (int j=0;j<4;++j){
        o[j]   += bf2f(vp[j]);
        eta[j] += sigmoidf(A[j] + bf2f(bp[j]));
      }
    } else ++nm;
  }

  const float fnm = (float)nm;
  float4 r;
  {
    float v0 = o[0] + eta[0] + fnm*sigmoidf(A[0]);
    float v1 = o[1] + eta[1] + fnm*sigmoidf(A[1]);
    float v2 = o[2] + eta[2] + fnm*sigmoidf(A[2]);
    float v3 = o[3] + eta[3] + fnm*sigmoidf(A[3]);
    r.x = v0>0.f?v0:0.f; r.y = v1>0.f?v1:0.f;
    r.z = v2>0.f?v2:0.f; r.w = v3>0.f?v3:0.f;
  }
  *reinterpret_cast<float4*>(out + (size_t)p*HH + c4) = r;
}

extern "C" void kernel_launch(void* const* d_in, const int* in_sizes, int n_in,
                              void* d_out, int out_size, void* d_ws, size_t ws_size,
                              hipStream_t stream)
{
  const float* prev = (const float*)d_in[0];
  const float* W_U  = (const float*)d_in[1];
  const float* W_V  = (const float*)d_in[2];
  const float* W_A  = (const float*)d_in[3];
  const float* W_B  = (const float*)d_in[4];
  const int* parent = (const int*)d_in[5];
  const int* child  = (const int*)d_in[6];
  const int* mask   = (const int*)d_in[7];
  float* out = (float*)d_out;

  const int n_nodes = in_sizes[5];

  unsigned short* wb = (unsigned short*)d_ws;      // [1024][256] bf16 (A,U,V,B rows)
  unsigned short* px = wb + 4*65536;               // [N][1024] bf16

  dim3 gc(32, 4);
  cvt_w<<<gc, 256, 0, stream>>>(W_A, W_U, W_V, W_B, wb);

  gemm_all<<<(n_nodes + 127)/128, 512, 0, stream>>>(prev, wb, px, n_nodes);

  epilogue<<<(n_nodes + 3)/4, 256, 0, stream>>>(px, parent, child, mask, out, n_nodes);
}